// Round 2
// baseline (213.980 us; speedup 1.0000x reference)
//
#include <hip/hip_runtime.h>
#include <hip/hip_bf16.h>

#define B 64
#define T 1024
#define C 768
#define TSPLIT 32           // t-chunks for partial reductions
#define TCHUNK (T / TSPLIT) // 32

// ---------------- ws layout (float offsets) ----------------
#define OFF_MSUM   64
#define OFF_ASUM   (OFF_MSUM + B*TSPLIT*C)
#define OFF_QSAL   (OFF_ASUM + B*TSPLIT*C)
#define OFF_Q      (OFF_QSAL + B*C)
#define OFF_QK     (OFF_Q + B*C)
#define OFF_SCORES (OFF_QK + B*C)
#define OFF_MPART  (OFF_SCORES + B*T)
#define OFF_SPART  (OFF_MPART + B*TSPLIT)
#define OFF_COEF   (OFF_SPART + B*TSPLIT)
#define OFF_PPART  (OFF_COEF + B*TSPLIT)
#define OFF_POOLED (OFF_PPART + B*TSPLIT*C)

__device__ __forceinline__ bool read_mask(const void* mask, int mode, int idx) {
    if (mode == 1) return ((const unsigned char*)mask)[idx] != 0;
    if (mode == 2) return ((const float*)mask)[idx] != 0.0f;
    return ((const int*)mask)[idx] != 0;
}

// K0: detect mask dtype. Reads only first 64KB (= bool-size of B*T mask).
__global__ void k_detect(const void* mask, int* mode_out) {
    __shared__ int s_not01, s_isf;
    int tid = threadIdx.x;
    if (tid == 0) { s_not01 = 0; s_isf = 0; }
    __syncthreads();
    const int* mi = (const int*)mask;
    int not01 = 0, isf = 0;
    for (int k = 0; k < 64; ++k) {
        int v = mi[tid + 256 * k];      // 256*64 = 16384 ints = 64KB
        if (v != 0 && v != 1) not01 = 1;
        if (v == 0x3F800000) isf = 1;
    }
    if (not01) atomicOr(&s_not01, 1);
    if (isf)   atomicOr(&s_isf, 1);
    __syncthreads();
    if (tid == 0) *mode_out = s_isf ? 2 : (s_not01 ? 1 : 0);
}

// K_A: per (b, t-chunk): partial masked-sum and all-sum. 192 thr, float4/thread.
__global__ void k_partial_sums(const float* __restrict__ tokens, const void* mask,
                               const int* modep, float* __restrict__ msum,
                               float* __restrict__ asum) {
    int ts = blockIdx.x, b = blockIdx.y, tid = threadIdx.x;
    int mode = *modep;
    __shared__ float s_m[TCHUNK];
    if (tid < TCHUNK)
        s_m[tid] = read_mask(mask, mode, b * T + ts * TCHUNK + tid) ? 1.f : 0.f;
    __syncthreads();
    int c = tid * 4;
    float4 ms = {0, 0, 0, 0}, as = {0, 0, 0, 0};
    const float* tb = tokens + (size_t)b * T * C;
#pragma unroll 4
    for (int r = 0; r < TCHUNK; ++r) {
        int t = ts * TCHUNK + r;
        float4 x = *(const float4*)(tb + (size_t)t * C + c);
        as.x += x.x; as.y += x.y; as.z += x.z; as.w += x.w;
        float wm = s_m[r];
        ms.x += wm * x.x; ms.y += wm * x.y; ms.z += wm * x.z; ms.w += wm * x.w;
    }
    size_t o = (size_t)(b * TSPLIT + ts) * C + c;
    *(float4*)(msum + o) = ms;
    *(float4*)(asum + o) = as;
}

// K_B: per b: cnt, then q_sal[b,c].
__global__ void k_qsal(const void* mask, const int* modep,
                       const float* __restrict__ msum, const float* __restrict__ asum,
                       float* __restrict__ qsal) {
    int b = blockIdx.x, tid = threadIdx.x;
    int mode = *modep;
    __shared__ float red[256];
    float cnt0 = 0.f;
    for (int t = tid; t < T; t += 256)
        cnt0 += read_mask(mask, mode, b * T + t) ? 1.f : 0.f;
    red[tid] = cnt0;
    __syncthreads();
    for (int s = 128; s > 0; s >>= 1) {
        if (tid < s) red[tid] += red[tid + s];
        __syncthreads();
    }
    float cnt = red[0];
    float scale = (cnt > 0.f) ? (1.f / fmaxf(cnt, 1.f)) : (1.f / (float)T);
    bool use_masked = (cnt > 0.f);
    for (int c = tid; c < C; c += 256) {
        float m = 0.f, a = 0.f;
#pragma unroll 8
        for (int p = 0; p < TSPLIT; ++p) {
            m += msum[(size_t)(b * TSPLIT + p) * C + c];
            a += asum[(size_t)(b * TSPLIT + p) * C + c];
        }
        qsal[b * C + c] = (use_masked ? m : a) * scale;
    }
}

// K_C: out[b,d] = scale * sum_c vin[b,c] * W[d,c]. 4 lanes cooperate per output.
__global__ void k_rowdot4(const float* __restrict__ vin, const float* __restrict__ W,
                          float* __restrict__ vout, float scale) {
    int tid = threadIdx.x;
    int gid = blockIdx.x * 64 + (tid >> 2);
    int sub = tid & 3;
    int b = gid / C, d = gid - b * C;
    const float4* v = (const float4*)(vin + (size_t)b * C);
    const float4* w = (const float4*)(W + (size_t)d * C);
    float acc = 0.f;
    int j0 = sub * 48;
#pragma unroll 8
    for (int j = j0; j < j0 + 48; ++j) {
        float4 a = v[j], x = w[j];
        acc += a.x * x.x + a.y * x.y + a.z * x.z + a.w * x.w;
    }
    acc += __shfl_xor(acc, 1);
    acc += __shfl_xor(acc, 2);
    if (sub == 0) vout[gid] = acc * scale;
}

// K_D: qk[b,c] = (1/sqrt(C)) * sum_d Q[b,d] * Wk[d,c]. 4 lanes per output over d.
__global__ void k_coldot4(const float* __restrict__ Q, const float* __restrict__ Wk,
                          float* __restrict__ qk) {
    int tid = threadIdx.x;
    int gid = blockIdx.x * 64 + (tid >> 2);
    int sub = tid & 3;
    int b = gid / C, c = gid - b * C;
    const float* Qb = Q + (size_t)b * C;
    float acc = 0.f;
    int d0 = sub * 192;
#pragma unroll 8
    for (int i = 0; i < 192; ++i) {
        int d = d0 + i;
        acc += Qb[d] * Wk[(size_t)d * C + c];
    }
    acc += __shfl_xor(acc, 1);
    acc += __shfl_xor(acc, 2);
    if (sub == 0) qk[gid] = acc * 0.03608439182435161f; // 1/sqrt(768)
}

// K_E: fused scores + partial softmax + partial pool per (b, t-chunk).
// 192 threads = 3 waves. Phase1: wave-per-row dot. Phase3: float4-per-thread pool.
__global__ void k_fused(const float* __restrict__ tokens, const float* __restrict__ qk,
                        float* __restrict__ scores, float* __restrict__ mpart,
                        float* __restrict__ spart, float* __restrict__ ppart) {
    __shared__ float sq[C];
    __shared__ float ssc[TCHUNK];
    __shared__ float sw[TCHUNK];
    int ts = blockIdx.x, b = blockIdx.y, tid = threadIdx.x;
    // load qk into LDS (192 x float4 = 768)
    ((float4*)sq)[tid] = ((const float4*)(qk + (size_t)b * C))[tid];
    __syncthreads();
    int wave = tid >> 6, lane = tid & 63;
    const float* tb = tokens + (size_t)b * T * C;
    const float4* q4 = (const float4*)sq;
    for (int r = wave; r < TCHUNK; r += 3) {
        int t = ts * TCHUNK + r;
        const float4* row = (const float4*)(tb + (size_t)t * C);
        float acc = 0.f;
#pragma unroll
        for (int j = 0; j < 3; ++j) {
            int idx = lane + 64 * j;   // 192 float4 = 768 floats
            float4 x = row[idx], q = q4[idx];
            acc += x.x * q.x + x.y * q.y + x.z * q.z + x.w * q.w;
        }
        for (int s = 32; s > 0; s >>= 1) acc += __shfl_xor(acc, s);
        if (lane == 0) { ssc[r] = acc; scores[(size_t)b * T + t] = acc; }
    }
    __syncthreads();
    float m = -3.4e38f;
#pragma unroll
    for (int r = 0; r < TCHUNK; ++r) m = fmaxf(m, ssc[r]);
    if (tid < TCHUNK) sw[tid] = expf(ssc[tid] - m);
    __syncthreads();
    float s = 0.f;
#pragma unroll
    for (int r = 0; r < TCHUNK; ++r) s += sw[r];
    // phase 3: weighted pool of this chunk
    int c = tid * 4;
    float4 acc = {0, 0, 0, 0};
#pragma unroll 4
    for (int r = 0; r < TCHUNK; ++r) {
        int t = ts * TCHUNK + r;
        float wv = sw[r];
        float4 x = *(const float4*)(tb + (size_t)t * C + c);
        acc.x += wv * x.x; acc.y += wv * x.y; acc.z += wv * x.z; acc.w += wv * x.w;
    }
    *(float4*)(ppart + (size_t)(b * TSPLIT + ts) * C + c) = acc;
    if (tid == 0) { mpart[b * TSPLIT + ts] = m; spart[b * TSPLIT + ts] = s; }
}

// K_F: combine chunk partials -> attn (d_out) + coef per chunk.
__global__ void k_combine(const float* __restrict__ scores, const float* __restrict__ mpart,
                          const float* __restrict__ spart, float* __restrict__ coef,
                          float* __restrict__ attn) {
    int b = blockIdx.x, tid = threadIdx.x;
    __shared__ float sm[TSPLIT], ss[TSPLIT];
    if (tid < TSPLIT) { sm[tid] = mpart[b * TSPLIT + tid]; ss[tid] = spart[b * TSPLIT + tid]; }
    __syncthreads();
    float M = -3.4e38f;
#pragma unroll
    for (int p = 0; p < TSPLIT; ++p) M = fmaxf(M, sm[p]);
    float Z = 0.f;
#pragma unroll
    for (int p = 0; p < TSPLIT; ++p) Z += ss[p] * expf(sm[p] - M);
    float invZ = 1.f / Z;
    if (tid < TSPLIT) coef[b * TSPLIT + tid] = expf(sm[tid] - M) * invZ;
    float4 sc = ((const float4*)(scores + (size_t)b * T))[tid];
    float4 o;
    o.x = expf(sc.x - M) * invZ; o.y = expf(sc.y - M) * invZ;
    o.z = expf(sc.z - M) * invZ; o.w = expf(sc.w - M) * invZ;
    ((float4*)(attn + (size_t)b * T))[tid] = o;
}

// K_G: pooled[b,c] = sum_ts coef[b,ts] * ppart[b,ts,c].
__global__ void k_pool_reduce(const float* __restrict__ ppart, const float* __restrict__ coef,
                              float* __restrict__ pooled) {
    int gid = blockIdx.x * 256 + threadIdx.x;
    int b = gid / C, c = gid - b * C;
    float a = 0.f;
#pragma unroll 8
    for (int p = 0; p < TSPLIT; ++p)
        a += coef[b * TSPLIT + p] * ppart[(size_t)(b * TSPLIT + p) * C + c];
    pooled[gid] = a;
}

extern "C" void kernel_launch(void* const* d_in, const int* in_sizes, int n_in,
                              void* d_out, int out_size, void* d_ws, size_t ws_size,
                              hipStream_t stream) {
    const float* tokens = (const float*)d_in[0];
    const void*  mask   = d_in[1];
    const float* Wq     = (const float*)d_in[2];
    const float* Wk     = (const float*)d_in[3];
    const float* Wv     = (const float*)d_in[4];

    float* ws     = (float*)d_ws;
    int*   mode   = (int*)d_ws;
    float* msum   = ws + OFF_MSUM;
    float* asum   = ws + OFF_ASUM;
    float* qsal   = ws + OFF_QSAL;
    float* Qv     = ws + OFF_Q;
    float* qk     = ws + OFF_QK;
    float* scores = ws + OFF_SCORES;
    float* mpart  = ws + OFF_MPART;
    float* spart  = ws + OFF_SPART;
    float* coef   = ws + OFF_COEF;
    float* ppart  = ws + OFF_PPART;
    float* pooled = ws + OFF_POOLED;

    float* v_fg = (float*)d_out;            // [B][C]
    float* attn = (float*)d_out + B * C;    // [B][T]

    k_detect<<<1, 256, 0, stream>>>(mask, mode);
    k_partial_sums<<<dim3(TSPLIT, B), 192, 0, stream>>>(tokens, mask, mode, msum, asum);
    k_qsal<<<B, 256, 0, stream>>>(mask, mode, msum, asum, qsal);
    k_rowdot4<<<(B * C) / 64, 256, 0, stream>>>(qsal, Wq, Qv, 1.0f);      // Q
    k_coldot4<<<(B * C) / 64, 256, 0, stream>>>(Qv, Wk, qk);              // qk (pre-scaled)
    k_fused<<<dim3(TSPLIT, B), 192, 0, stream>>>(tokens, qk, scores, mpart, spart, ppart);
    k_combine<<<B, 256, 0, stream>>>(scores, mpart, spart, coef, attn);
    k_pool_reduce<<<(B * C) / 256, 256, 0, stream>>>(ppart, coef, pooled);
    k_rowdot4<<<(B * C) / 64, 256, 0, stream>>>(pooled, Wv, v_fg, 1.0f);  // v_fg
}

// Round 3
// 172.368 us; speedup vs baseline: 1.2414x; 1.2414x over previous
//
#include <hip/hip_runtime.h>
#include <hip/hip_bf16.h>

#define B 64
#define T 1024
#define C 768
#define TSPLIT 32           // t-chunks for partial reductions
#define TCHUNK (T / TSPLIT) // 32

// ---------------- ws layout (float offsets) ----------------
#define OFF_MSUM   64
#define OFF_ASUM   (OFF_MSUM + B*TSPLIT*C)
#define OFF_CNT    (OFF_ASUM + B*TSPLIT*C)
#define OFF_Q      (OFF_CNT + B*TSPLIT)
#define OFF_QK     (OFF_Q + B*C)
#define OFF_SCORES (OFF_QK + B*C)
#define OFF_MPART  (OFF_SCORES + B*T)
#define OFF_SPART  (OFF_MPART + B*TSPLIT)
#define OFF_PPART  (OFF_SPART + B*TSPLIT)

__device__ __forceinline__ bool read_mask(const void* mask, int mode, int idx) {
    if (mode == 1) return ((const unsigned char*)mask)[idx] != 0;
    if (mode == 2) return ((const float*)mask)[idx] != 0.0f;
    return ((const int*)mask)[idx] != 0;
}

// K0: detect mask dtype. Reads only first 64KB (= bool-size of B*T mask).
__global__ void k_detect(const void* mask, int* mode_out) {
    __shared__ int s_not01, s_isf;
    int tid = threadIdx.x;
    if (tid == 0) { s_not01 = 0; s_isf = 0; }
    __syncthreads();
    const int* mi = (const int*)mask;
    int not01 = 0, isf = 0;
    for (int k = 0; k < 64; ++k) {
        int v = mi[tid + 256 * k];      // 256*64 = 16384 ints = 64KB
        if (v != 0 && v != 1) not01 = 1;
        if (v == 0x3F800000) isf = 1;
    }
    if (not01) atomicOr(&s_not01, 1);
    if (isf)   atomicOr(&s_isf, 1);
    __syncthreads();
    if (tid == 0) *mode_out = s_isf ? 2 : (s_not01 ? 1 : 0);
}

// K1: per (b, t-chunk): partial masked-sum, all-sum, mask count.
__global__ __launch_bounds__(192) void
k_pass1(const float* __restrict__ tokens, const void* mask, const int* modep,
        float* __restrict__ msum, float* __restrict__ asum, float* __restrict__ cntpart) {
    int ts = blockIdx.x, b = blockIdx.y, tid = threadIdx.x;
    int mode = *modep;
    __shared__ float s_m[TCHUNK];
    if (tid < TCHUNK)
        s_m[tid] = read_mask(mask, mode, b * T + ts * TCHUNK + tid) ? 1.f : 0.f;
    __syncthreads();
    int c = tid * 4;
    float4 ms = {0, 0, 0, 0}, as = {0, 0, 0, 0};
    const float* tb = tokens + (size_t)b * T * C;
#pragma unroll 4
    for (int r = 0; r < TCHUNK; ++r) {
        int t = ts * TCHUNK + r;
        float4 x = *(const float4*)(tb + (size_t)t * C + c);
        as.x += x.x; as.y += x.y; as.z += x.z; as.w += x.w;
        float wm = s_m[r];
        ms.x += wm * x.x; ms.y += wm * x.y; ms.z += wm * x.z; ms.w += wm * x.w;
    }
    size_t o = (size_t)(b * TSPLIT + ts) * C + c;
    *(float4*)(msum + o) = ms;
    *(float4*)(asum + o) = as;
    if (tid == 0) {
        float cnt = 0.f;
#pragma unroll
        for (int r = 0; r < TCHUNK; ++r) cnt += s_m[r];
        cntpart[b * TSPLIT + ts] = cnt;
    }
}

// K2: per block (12 per b): reduce partials -> qsal (LDS), then 64 Q outputs.
__global__ __launch_bounds__(256) void
k_qsal_rowdot(const float* __restrict__ msum, const float* __restrict__ asum,
              const float* __restrict__ cntpart, const float* __restrict__ Wq,
              float* __restrict__ Qv) {
    int b = blockIdx.y, tid = threadIdx.x;
    __shared__ float sq[C];
    float cnt = 0.f;
#pragma unroll
    for (int p = 0; p < TSPLIT; ++p) cnt += cntpart[b * TSPLIT + p];
    bool um = (cnt > 0.f);
    float scale = um ? (1.f / fmaxf(cnt, 1.f)) : (1.f / (float)T);
    const float* src = um ? msum : asum;
    for (int c = tid; c < C; c += 256) {
        float a = 0.f;
#pragma unroll 8
        for (int p = 0; p < TSPLIT; ++p) a += src[(size_t)(b * TSPLIT + p) * C + c];
        sq[c] = a * scale;
    }
    __syncthreads();
    int d = blockIdx.x * 64 + (tid >> 2), sub = tid & 3;
    const float4* w = (const float4*)(Wq + (size_t)d * C);
    const float4* v4 = (const float4*)sq;
    float acc = 0.f;
#pragma unroll 8
    for (int j = sub * 48; j < sub * 48 + 48; ++j) {
        float4 a = v4[j], x = w[j];
        acc += a.x * x.x + a.y * x.y + a.z * x.z + a.w * x.w;
    }
    acc += __shfl_xor(acc, 1);
    acc += __shfl_xor(acc, 2);
    if (sub == 0) Qv[b * C + d] = acc;
}

// K3: qk[b,c] = (1/sqrt(C)) * sum_d Q[b,d] * Wk[d,c]. Q staged in LDS.
__global__ __launch_bounds__(256) void
k_coldot(const float* __restrict__ Qv, const float* __restrict__ Wk,
         float* __restrict__ qk) {
    int b = blockIdx.y, tid = threadIdx.x;
    __shared__ float sQ[C];
    for (int c = tid; c < C; c += 256) sQ[c] = Qv[b * C + c];
    __syncthreads();
    int c = blockIdx.x * 64 + (tid >> 2), sub = tid & 3;
    float acc = 0.f;
#pragma unroll 8
    for (int i = 0; i < 192; ++i) {
        int d = sub * 192 + i;
        acc += sQ[d] * Wk[(size_t)d * C + c];
    }
    acc += __shfl_xor(acc, 1);
    acc += __shfl_xor(acc, 2);
    if (sub == 0) qk[b * C + c] = acc * 0.03608439182435161f; // 1/sqrt(768)
}

// K4: fused scores + chunk softmax partials + chunk weighted pool.
__global__ __launch_bounds__(192) void
k_fused(const float* __restrict__ tokens, const float* __restrict__ qk,
        float* __restrict__ scores, float* __restrict__ mpart,
        float* __restrict__ spart, float* __restrict__ ppart) {
    __shared__ float sq[C];
    __shared__ float ssc[TCHUNK];
    __shared__ float sw[TCHUNK];
    int ts = blockIdx.x, b = blockIdx.y, tid = threadIdx.x;
    ((float4*)sq)[tid] = ((const float4*)(qk + (size_t)b * C))[tid];
    __syncthreads();
    int wave = tid >> 6, lane = tid & 63;
    const float* tb = tokens + (size_t)b * T * C;
    const float4* q4 = (const float4*)sq;
    for (int r = wave; r < TCHUNK; r += 3) {
        int t = ts * TCHUNK + r;
        const float4* row = (const float4*)(tb + (size_t)t * C);
        float acc = 0.f;
#pragma unroll
        for (int j = 0; j < 3; ++j) {
            int idx = lane + 64 * j;   // 192 float4 = 768 floats
            float4 x = row[idx], q = q4[idx];
            acc += x.x * q.x + x.y * q.y + x.z * q.z + x.w * q.w;
        }
        for (int s = 32; s > 0; s >>= 1) acc += __shfl_xor(acc, s);
        if (lane == 0) { ssc[r] = acc; scores[(size_t)b * T + t] = acc; }
    }
    __syncthreads();
    float m = -3.4e38f;
#pragma unroll
    for (int r = 0; r < TCHUNK; ++r) m = fmaxf(m, ssc[r]);
    if (tid < TCHUNK) sw[tid] = expf(ssc[tid] - m);
    __syncthreads();
    float s = 0.f;
#pragma unroll
    for (int r = 0; r < TCHUNK; ++r) s += sw[r];
    int c = tid * 4;
    float4 acc = {0, 0, 0, 0};
#pragma unroll 4
    for (int r = 0; r < TCHUNK; ++r) {
        int t = ts * TCHUNK + r;
        float wv = sw[r];
        float4 x = *(const float4*)(tb + (size_t)t * C + c);
        acc.x += wv * x.x; acc.y += wv * x.y; acc.z += wv * x.z; acc.w += wv * x.w;
    }
    *(float4*)(ppart + (size_t)(b * TSPLIT + ts) * C + c) = acc;
    if (tid == 0) { mpart[b * TSPLIT + ts] = m; spart[b * TSPLIT + ts] = s; }
}

// K5: global softmax combine -> attn (d_out).
__global__ __launch_bounds__(256) void
k_attn(const float* __restrict__ scores, const float* __restrict__ mpart,
       const float* __restrict__ spart, float* __restrict__ attn) {
    int b = blockIdx.x, tid = threadIdx.x;
    float M = -3.4e38f;
#pragma unroll
    for (int p = 0; p < TSPLIT; ++p) M = fmaxf(M, mpart[b * TSPLIT + p]);
    float Z = 0.f;
#pragma unroll
    for (int p = 0; p < TSPLIT; ++p) Z += spart[b * TSPLIT + p] * expf(mpart[b * TSPLIT + p] - M);
    float invZ = 1.f / Z;
    float4 sc = ((const float4*)(scores + (size_t)b * T))[tid];
    float4 o;
    o.x = expf(sc.x - M) * invZ; o.y = expf(sc.y - M) * invZ;
    o.z = expf(sc.z - M) * invZ; o.w = expf(sc.w - M) * invZ;
    ((float4*)(attn + (size_t)b * T))[tid] = o;
}

// K6: per block (12 per b): recompute coef, build pooled in LDS, 64 v_fg outputs.
__global__ __launch_bounds__(256) void
k_vfg(const float* __restrict__ ppart, const float* __restrict__ mpart,
      const float* __restrict__ spart, const float* __restrict__ Wv,
      float* __restrict__ vfg) {
    int b = blockIdx.y, tid = threadIdx.x;
    __shared__ float sp[C];
    float M = -3.4e38f;
#pragma unroll
    for (int p = 0; p < TSPLIT; ++p) M = fmaxf(M, mpart[b * TSPLIT + p]);
    float Z = 0.f;
#pragma unroll
    for (int p = 0; p < TSPLIT; ++p) Z += spart[b * TSPLIT + p] * expf(mpart[b * TSPLIT + p] - M);
    float invZ = 1.f / Z;
    float coef[TSPLIT];
#pragma unroll
    for (int p = 0; p < TSPLIT; ++p) coef[p] = expf(mpart[b * TSPLIT + p] - M) * invZ;
    for (int c = tid; c < C; c += 256) {
        float a = 0.f;
#pragma unroll 8
        for (int p = 0; p < TSPLIT; ++p)
            a += coef[p] * ppart[(size_t)(b * TSPLIT + p) * C + c];
        sp[c] = a;
    }
    __syncthreads();
    int d = blockIdx.x * 64 + (tid >> 2), sub = tid & 3;
    const float4* w = (const float4*)(Wv + (size_t)d * C);
    const float4* v4 = (const float4*)sp;
    float acc = 0.f;
#pragma unroll 8
    for (int j = sub * 48; j < sub * 48 + 48; ++j) {
        float4 a = v4[j], x = w[j];
        acc += a.x * x.x + a.y * x.y + a.z * x.z + a.w * x.w;
    }
    acc += __shfl_xor(acc, 1);
    acc += __shfl_xor(acc, 2);
    if (sub == 0) vfg[b * C + d] = acc;
}

extern "C" void kernel_launch(void* const* d_in, const int* in_sizes, int n_in,
                              void* d_out, int out_size, void* d_ws, size_t ws_size,
                              hipStream_t stream) {
    const float* tokens = (const float*)d_in[0];
    const void*  mask   = d_in[1];
    const float* Wq     = (const float*)d_in[2];
    const float* Wk     = (const float*)d_in[3];
    const float* Wv     = (const float*)d_in[4];

    float* ws      = (float*)d_ws;
    int*   mode    = (int*)d_ws;
    float* msum    = ws + OFF_MSUM;
    float* asum    = ws + OFF_ASUM;
    float* cntpart = ws + OFF_CNT;
    float* Qv      = ws + OFF_Q;
    float* qk      = ws + OFF_QK;
    float* scores  = ws + OFF_SCORES;
    float* mpart   = ws + OFF_MPART;
    float* spart   = ws + OFF_SPART;
    float* ppart   = ws + OFF_PPART;

    float* v_fg = (float*)d_out;            // [B][C]
    float* attn = (float*)d_out + B * C;    // [B][T]

    k_detect<<<1, 256, 0, stream>>>(mask, mode);
    k_pass1<<<dim3(TSPLIT, B), 192, 0, stream>>>(tokens, mask, mode, msum, asum, cntpart);
    k_qsal_rowdot<<<dim3(12, B), 256, 0, stream>>>(msum, asum, cntpart, Wq, Qv);
    k_coldot<<<dim3(12, B), 256, 0, stream>>>(Qv, Wk, qk);
    k_fused<<<dim3(TSPLIT, B), 192, 0, stream>>>(tokens, qk, scores, mpart, spart, ppart);
    k_attn<<<B, 256, 0, stream>>>(scores, mpart, spart, attn);
    k_vfg<<<dim3(12, B), 256, 0, stream>>>(ppart, mpart, spart, Wv, v_fg);
}